// Round 7
// baseline (476.176 us; speedup 1.0000x reference)
//
#include <hip/hip_runtime.h>
#include <math.h>

#define V_ 32000
#define E_ 1024
#define H_ 1024
#define S_ 2048
#define NB 1536

typedef __attribute__((ext_vector_type(8))) short bf16x8;
typedef __attribute__((ext_vector_type(8))) unsigned short u16x8;
typedef __attribute__((ext_vector_type(4))) float f32x4;

typedef __attribute__((address_space(1))) const unsigned int gu32;
typedef __attribute__((address_space(3))) unsigned int lu32;

__device__ __forceinline__ float sigmoidf_(float x) { return 1.0f / (1.0f + expf(-x)); }

__device__ __forceinline__ unsigned short f2bf(float f) {
    unsigned int u = __builtin_bit_cast(unsigned int, f);
    unsigned int r = (u + 0x7fffu + ((u >> 16) & 1u)) >> 16;
    return (unsigned short)r;
}
__device__ __forceinline__ float bf2f(unsigned short u) {
    return __builtin_bit_cast(float, ((unsigned int)u) << 16);
}
__device__ __forceinline__ u16x8 pack8(float4 a, float4 b) {
    u16x8 p;
    p[0] = f2bf(a.x); p[1] = f2bf(a.y); p[2] = f2bf(a.z); p[3] = f2bf(a.w);
    p[4] = f2bf(b.x); p[5] = f2bf(b.y); p[6] = f2bf(b.z); p[7] = f2bf(b.w);
    return p;
}
__device__ __forceinline__ void gload16(const void* g, void* l) {
    __builtin_amdgcn_global_load_lds((gu32*)g, (lu32*)l, 16, 0, 0);
}

// ---- RMW-free barrier: per-block flag store; block 0 aggregates -> go word ----
__device__ __forceinline__ void bar_release(unsigned* flags, int bid) {
    __syncthreads();
    if (threadIdx.x == 0) {
        __builtin_amdgcn_fence(__ATOMIC_RELEASE, "agent");
        __hip_atomic_store(&flags[bid], 1u, __ATOMIC_RELAXED, __HIP_MEMORY_SCOPE_AGENT);
    }
}
__device__ __forceinline__ void bar_aggregate(unsigned* flags, int n, unsigned* go) {
    for (int i = threadIdx.x; i < n; i += 256) {
        int iter = 0;
        while (__hip_atomic_load(&flags[i], __ATOMIC_RELAXED, __HIP_MEMORY_SCOPE_AGENT) == 0u) {
            __builtin_amdgcn_s_sleep(16);
            if (++iter > 200000) break;   // bounded (never triggers when correct)
        }
    }
    __syncthreads();
    if (threadIdx.x == 0) {
        __builtin_amdgcn_fence(__ATOMIC_ACQUIRE, "agent");
        __builtin_amdgcn_fence(__ATOMIC_RELEASE, "agent");
        __hip_atomic_store(go, 1u, __ATOMIC_RELAXED, __HIP_MEMORY_SCOPE_AGENT);
    }
}
__device__ __forceinline__ void bar_wait(unsigned* go) {
    if (threadIdx.x == 0) {
        int iter = 0;
        while (__hip_atomic_load(go, __ATOMIC_RELAXED, __HIP_MEMORY_SCOPE_AGENT) == 0u) {
            __builtin_amdgcn_s_sleep(32);
            if (++iter > 200000) break;
        }
    }
    __syncthreads();
    __builtin_amdgcn_fence(__ATOMIC_ACQUIRE, "agent");
}

struct Params {
    const float *enc, *last_context, *h0, *c0, *emb;
    const float *W_ih, *W_hh, *b_ih, *b_hh;
    const float *W_attn, *b_attn, *v, *W_ah, *b_ah, *W_out, *b_out;
    const int* word;
    float *out_logits, *out_ht, *out_c, *out_htt, *out_w;
    float *ws_ht, *ws_q, *ws_htt, *gpart, *ctx, *lpart, *spart;
    unsigned *flagsB, *flags1, *go;   // flagsB: 5 x NB, flags1: 1024, go: 8
    unsigned short *encb, *wab;
};

__global__ __launch_bounds__(64) void zeroK(unsigned* syncarea, int nsync, float* ctx) {
    int i = blockIdx.x * 64 + threadIdx.x;
    if (i < nsync) syncarea[i] = 0u;
    if (i < E_) ctx[i] = 0.f;
}

__global__ __launch_bounds__(256, 6) void mega(Params p)
{
    __shared__ unsigned short AsBs[8192];   // 16 KB: As=0..4095, Bs=4096..8191
    __shared__ float fsm[64];
    const int b = blockIdx.x, tid = threadIdx.x;
    const int wave = tid >> 6, lane = tid & 63;

    // ================= P0: LSTM (b<1024) || bf16 conversion (1024..1535) =================
    if (b < 1024) {
        int j = b;
        const float* embrow = p.emb + (size_t)p.word[0] * E_;
        int row = j + wave * H_;
        const float* wi = p.W_ih + (size_t)row * (E_ + H_);
        const float* wh = p.W_hh + (size_t)row * H_;
        float acc = 0.f;
        #pragma unroll
        for (int it = 0; it < 8; ++it) {
            int idx = (lane + it * 64) * 4;
            float4 wv = *(const float4*)(wi + idx);
            float4 xv = (idx < H_) ? *(const float4*)(p.last_context + idx)
                                   : *(const float4*)(embrow + (idx - H_));
            acc = fmaf(wv.x, xv.x, acc); acc = fmaf(wv.y, xv.y, acc);
            acc = fmaf(wv.z, xv.z, acc); acc = fmaf(wv.w, xv.w, acc);
        }
        #pragma unroll
        for (int it = 0; it < 4; ++it) {
            int idx = (lane + it * 64) * 4;
            float4 wv = *(const float4*)(wh + idx);
            float4 hv = *(const float4*)(p.h0 + idx);
            acc = fmaf(wv.x, hv.x, acc); acc = fmaf(wv.y, hv.y, acc);
            acc = fmaf(wv.z, hv.z, acc); acc = fmaf(wv.w, hv.w, acc);
        }
        #pragma unroll
        for (int m = 32; m; m >>= 1) acc += __shfl_down(acc, m, 64);
        if (lane == 0) fsm[wave] = acc;
        __syncthreads();
        if (tid == 0) {
            float gi = fsm[0] + p.b_ih[j]          + p.b_hh[j];
            float gf = fsm[1] + p.b_ih[j + H_]     + p.b_hh[j + H_];
            float gg = fsm[2] + p.b_ih[j + 2*H_]   + p.b_hh[j + 2*H_];
            float go_ = fsm[3] + p.b_ih[j + 3*H_]  + p.b_hh[j + 3*H_];
            float c  = sigmoidf_(gf) * p.c0[j] + sigmoidf_(gi) * tanhf(gg);
            float ht = sigmoidf_(go_) * tanhf(c);
            p.out_c[j]  = c;
            p.out_ht[j] = ht;
            p.ws_ht[j]  = ht;
        }
    } else {
        int cid = (b - 1024) * 256 + tid;
        const int ENC_CH = (S_ * E_) / 8;   // 262144
        #pragma unroll
        for (int i = 0; i < 3; ++i) {
            int idx = cid + i * 131072;
            const float* src;
            unsigned short* dst;
            if (idx < ENC_CH) {
                src = p.enc + (size_t)idx * 8;
                dst = p.encb + (size_t)idx * 8;
            } else {
                int w = idx - ENC_CH;
                int h = w >> 7, off = (w & 127) * 8;
                src = p.W_attn + (size_t)h * (E_ + H_) + H_ + off;
                dst = p.wab + (size_t)h * E_ + off;
            }
            float4 a = *(const float4*)src;
            float4 bq = *(const float4*)(src + 4);
            *(u16x8*)dst = pack8(a, bq);
        }
    }
    bar_release(&p.flagsB[0 * NB], b);
    if (b == 0) bar_aggregate(&p.flagsB[0 * NB], NB, &p.go[0]);
    bar_wait(&p.go[0]);

    // ================= Group 1: q (blocks 512..1535) || GEMM main (blocks 0..511) =======
    if (b >= 512) {
        int r = b - 512;   // 0..1023
        const float* rowp = p.W_attn + (size_t)r * (E_ + H_);
        float acc = 0.f;
        {
            int idx = (wave * 64 + lane) * 4;
            float4 wv = *(const float4*)(rowp + idx);
            float4 hv = *(const float4*)(p.ws_ht + idx);
            acc = fmaf(wv.x, hv.x, acc); acc = fmaf(wv.y, hv.y, acc);
            acc = fmaf(wv.z, hv.z, acc); acc = fmaf(wv.w, hv.w, acc);
        }
        #pragma unroll
        for (int m = 32; m; m >>= 1) acc += __shfl_down(acc, m, 64);
        if (lane == 0) fsm[48 + wave] = acc;
        __syncthreads();
        if (tid == 0)
            p.ws_q[r] = fsm[48] + fsm[49] + fsm[50] + fsm[51] + p.b_attn[r];
        __syncthreads();
        if (tid == 0) {
            __builtin_amdgcn_fence(__ATOMIC_RELEASE, "agent");
            __hip_atomic_store(&p.flags1[r], 1u, __ATOMIC_RELAXED, __HIP_MEMORY_SCOPE_AGENT);
        }
    } else {
        // ---- GEMM: 64x64 tile; sb = b&31, hb = b>>5 ----
        unsigned short* As = AsBs;
        unsigned short* Bs = AsBs + 4096;
        int sb = b & 31, hb = b >> 5;
        int s0 = sb * 64, h0 = hb * 64;
        int r0 = tid >> 3, c = tid & 7;
        int lc = (c ^ (r0 & 7)) * 8;
        const unsigned short* aS0 = p.encb + (size_t)(s0 + r0) * E_ + lc;
        const unsigned short* aS1 = p.encb + (size_t)(s0 + 32 + r0) * E_ + lc;
        const unsigned short* bS0 = p.wab  + (size_t)(h0 + r0) * E_ + lc;
        const unsigned short* bS1 = p.wab  + (size_t)(h0 + 32 + r0) * E_ + lc;

        int wr = (wave >> 1) * 32, wc = (wave & 1) * 32;
        int fc = lane & 15, g = lane >> 4;
        int aRow[2], bRow[2], pc[2];
        #pragma unroll
        for (int m = 0; m < 2; ++m) aRow[m] = (wr + m * 16 + fc) * 64;
        #pragma unroll
        for (int n = 0; n < 2; ++n) bRow[n] = (wc + n * 16 + fc) * 64;
        #pragma unroll
        for (int kk = 0; kk < 2; ++kk) pc[kk] = ((kk * 4 + g) ^ (fc & 7)) * 8;

        f32x4 acc[2][2];
        #pragma unroll
        for (int m = 0; m < 2; ++m)
            #pragma unroll
            for (int n = 0; n < 2; ++n)
                acc[m][n] = (f32x4){0.f, 0.f, 0.f, 0.f};

        for (int t = 0; t < 16; ++t) {
            int k0 = t * 64;
            gload16(aS0 + k0, As + tid * 8);
            gload16(aS1 + k0, As + 2048 + tid * 8);
            gload16(bS0 + k0, Bs + tid * 8);
            gload16(bS1 + k0, Bs + 2048 + tid * 8);
            __syncthreads();
            #pragma unroll
            for (int kk = 0; kk < 2; ++kk) {
                bf16x8 af[2], bf2[2];
                #pragma unroll
                for (int m = 0; m < 2; ++m) af[m] = *(const bf16x8*)(As + aRow[m] + pc[kk]);
                #pragma unroll
                for (int n = 0; n < 2; ++n) bf2[n] = *(const bf16x8*)(Bs + bRow[n] + pc[kk]);
                #pragma unroll
                for (int m = 0; m < 2; ++m)
                    #pragma unroll
                    for (int n = 0; n < 2; ++n)
                        acc[m][n] = __builtin_amdgcn_mfma_f32_16x16x32_bf16(
                            af[m], bf2[n], acc[m][n], 0, 0, 0);
            }
            __syncthreads();
        }

        // wait for q (block 0 aggregates the 1024 q-flags into go[5])
        if (b == 0) bar_aggregate(p.flags1, 1024, &p.go[5]);
        bar_wait(&p.go[5]);

        float qv[2], vv[2];
        #pragma unroll
        for (int n = 0; n < 2; ++n) {
            int col = h0 + wc + n * 16 + fc;
            qv[n] = p.ws_q[col];
            vv[n] = p.v[col];
        }
        int part = hb * 2 + (wave & 1);
        #pragma unroll
        for (int m = 0; m < 2; ++m) {
            #pragma unroll
            for (int j = 0; j < 4; ++j) {
                float pp = 0.f;
                #pragma unroll
                for (int n = 0; n < 2; ++n)
                    pp += tanhf(acc[m][n][j] + qv[n]) * vv[n];
                #pragma unroll
                for (int mask = 8; mask; mask >>= 1) pp += __shfl_xor(pp, mask, 64);
                if (fc == 0)
                    p.spart[(size_t)(s0 + wr + m * 16 + g * 4 + j) * 32 + part] = pp;
            }
        }
    }
    bar_release(&p.flagsB[1 * NB], b);
    if (b == 0) bar_aggregate(&p.flagsB[1 * NB], NB, &p.go[1]);
    bar_wait(&p.go[1]);

    // ================= P3: exp + gpart + unnormalized ctx (blocks 0..255) ===============
    if (b < 256) {
        int s0p = b * 8;
        int sl = tid >> 5, pp2 = tid & 31;
        float vsum = p.spart[(size_t)(s0p + sl) * 32 + pp2];
        #pragma unroll
        for (int m = 16; m; m >>= 1) vsum += __shfl_xor(vsum, m, 64);
        if (pp2 == 0) fsm[8 + sl] = expf(vsum);
        __syncthreads();
        if (tid == 0) {
            float bs = 0.f;
            #pragma unroll
            for (int i = 0; i < 8; ++i) bs += fsm[8 + i];
            p.gpart[b] = bs;
        }
        int e0 = tid * 4;
        float a0 = 0.f, a1 = 0.f, a2 = 0.f, a3 = 0.f;
        #pragma unroll
        for (int ss = 0; ss < 8; ++ss) {
            ushort4 u = *(const ushort4*)(p.encb + (size_t)(s0p + ss) * E_ + e0);
            float w = fsm[8 + ss];
            a0 = fmaf(w, bf2f(u.x), a0);
            a1 = fmaf(w, bf2f(u.y), a1);
            a2 = fmaf(w, bf2f(u.z), a2);
            a3 = fmaf(w, bf2f(u.w), a3);
        }
        atomicAdd(&p.ctx[e0 + 0], a0);
        atomicAdd(&p.ctx[e0 + 1], a1);
        atomicAdd(&p.ctx[e0 + 2], a2);
        atomicAdd(&p.ctx[e0 + 3], a3);
    }
    bar_release(&p.flagsB[2 * NB], b);
    if (b == 0) bar_aggregate(&p.flagsB[2 * NB], NB, &p.go[2]);
    bar_wait(&p.go[2]);

    // ================= P4: invS, ht_tilda (blocks 0..511), out_w (0..255) ===============
    if (b < 512) {
        float gv = p.gpart[tid];
        #pragma unroll
        for (int m = 32; m; m >>= 1) gv += __shfl_xor(gv, m, 64);
        if (lane == 0) fsm[16 + wave] = gv;
        __syncthreads();
        float invS = 1.0f / (fsm[16] + fsm[17] + fsm[18] + fsm[19]);

        int r = b * 2 + (wave >> 1);
        int half = wave & 1;
        const float* rowp = p.W_ah + (size_t)r * (E_ + H_) + half * 1024;
        float acc = 0.f;
        #pragma unroll
        for (int it = 0; it < 4; ++it) {
            int idx = (lane + it * 64) * 4;
            float4 wv = *(const float4*)(rowp + idx);
            float4 xv;
            if (half == 0) {
                float4 cv = *(const float4*)(p.ctx + idx);
                xv = (float4){ cv.x * invS, cv.y * invS, cv.z * invS, cv.w * invS };
            } else {
                xv = *(const float4*)(p.ws_ht + idx);
            }
            acc = fmaf(wv.x, xv.x, acc); acc = fmaf(wv.y, xv.y, acc);
            acc = fmaf(wv.z, xv.z, acc); acc = fmaf(wv.w, xv.w, acc);
        }
        #pragma unroll
        for (int m = 32; m; m >>= 1) acc += __shfl_down(acc, m, 64);
        if (lane == 0) fsm[24 + wave] = acc;
        __syncthreads();
        if (tid == 0) {
            float val = tanhf(fsm[24] + fsm[25] + p.b_ah[b * 2]);
            p.out_htt[b * 2] = val; p.ws_htt[b * 2] = val;
        }
        if (tid == 128) {
            float val = tanhf(fsm[26] + fsm[27] + p.b_ah[b * 2 + 1]);
            p.out_htt[b * 2 + 1] = val; p.ws_htt[b * 2 + 1] = val;
        }
        if (b < 256 && tid < 8)
            p.out_w[b * 8 + tid] = fsm[8 + tid] * invS;
    }
    bar_release(&p.flagsB[3 * NB], b);
    if (b == 0) bar_aggregate(&p.flagsB[3 * NB], NB, &p.go[3]);
    bar_wait(&p.go[3]);

    // ================= P5: logits (6 rows per wave, batched loads) ======================
    {
        int rb = b * 4 + wave;
        int r5 = 30720 + rb;
        const float* w0 = p.W_out + (size_t)(rb)          * H_;
        const float* w1 = p.W_out + (size_t)(rb + 6144)   * H_;
        const float* w2 = p.W_out + (size_t)(rb + 12288)  * H_;
        const float* w3 = p.W_out + (size_t)(rb + 18432)  * H_;
        const float* w4 = p.W_out + (size_t)(rb + 24576)  * H_;
        const float* w5 = p.W_out + (size_t)((r5 < V_) ? r5 : 0) * H_;
        float a0 = 0.f, a1 = 0.f, a2 = 0.f, a3 = 0.f, a4 = 0.f, a5 = 0.f;
        #pragma unroll
        for (int it = 0; it < 4; ++it) {
            int idx = (lane + it * 64) * 4;
            float4 hv = *(const float4*)(p.ws_htt + idx);
            float4 v0 = *(const float4*)(w0 + idx);
            float4 v1 = *(const float4*)(w1 + idx);
            float4 v2 = *(const float4*)(w2 + idx);
            float4 v3 = *(const float4*)(w3 + idx);
            float4 v4 = *(const float4*)(w4 + idx);
            float4 v5 = *(const float4*)(w5 + idx);
            a0 = fmaf(v0.x, hv.x, a0); a0 = fmaf(v0.y, hv.y, a0); a0 = fmaf(v0.z, hv.z, a0); a0 = fmaf(v0.w, hv.w, a0);
            a1 = fmaf(v1.x, hv.x, a1); a1 = fmaf(v1.y, hv.y, a1); a1 = fmaf(v1.z, hv.z, a1); a1 = fmaf(v1.w, hv.w, a1);
            a2 = fmaf(v2.x, hv.x, a2); a2 = fmaf(v2.y, hv.y, a2); a2 = fmaf(v2.z, hv.z, a2); a2 = fmaf(v2.w, hv.w, a2);
            a3 = fmaf(v3.x, hv.x, a3); a3 = fmaf(v3.y, hv.y, a3); a3 = fmaf(v3.z, hv.z, a3); a3 = fmaf(v3.w, hv.w, a3);
            a4 = fmaf(v4.x, hv.x, a4); a4 = fmaf(v4.y, hv.y, a4); a4 = fmaf(v4.z, hv.z, a4); a4 = fmaf(v4.w, hv.w, a4);
            a5 = fmaf(v5.x, hv.x, a5); a5 = fmaf(v5.y, hv.y, a5); a5 = fmaf(v5.z, hv.z, a5); a5 = fmaf(v5.w, hv.w, a5);
        }
        #pragma unroll
        for (int m = 32; m; m >>= 1) {
            a0 += __shfl_down(a0, m, 64); a1 += __shfl_down(a1, m, 64);
            a2 += __shfl_down(a2, m, 64); a3 += __shfl_down(a3, m, 64);
            a4 += __shfl_down(a4, m, 64); a5 += __shfl_down(a5, m, 64);
        }
        float esum = 0.f;
        if (lane == 0) {
            float lg;
            lg = a0 + p.b_out[rb];          p.out_logits[rb]          = lg; esum += expf(lg);
            lg = a1 + p.b_out[rb + 6144];   p.out_logits[rb + 6144]   = lg; esum += expf(lg);
            lg = a2 + p.b_out[rb + 12288];  p.out_logits[rb + 12288]  = lg; esum += expf(lg);
            lg = a3 + p.b_out[rb + 18432];  p.out_logits[rb + 18432]  = lg; esum += expf(lg);
            lg = a4 + p.b_out[rb + 24576];  p.out_logits[rb + 24576]  = lg; esum += expf(lg);
            if (r5 < V_) {
                lg = a5 + p.b_out[r5];      p.out_logits[r5]          = lg; esum += expf(lg);
            }
            fsm[32 + wave] = esum;
        }
        __syncthreads();
        if (tid == 0)
            p.lpart[b] = fsm[32] + fsm[33] + fsm[34] + fsm[35];
    }
    bar_release(&p.flagsB[4 * NB], b);
    if (b == 0) bar_aggregate(&p.flagsB[4 * NB], NB, &p.go[4]);
    bar_wait(&p.go[4]);

    // ================= P6: lse (redundant per block) + subtract =========================
    {
        float s = 0.f;
        #pragma unroll
        for (int k = 0; k < 6; ++k) s += p.lpart[tid + k * 256];
        #pragma unroll
        for (int m = 32; m; m >>= 1) s += __shfl_down(s, m, 64);
        if (lane == 0) fsm[40 + wave] = s;
        __syncthreads();
        if (tid == 0) fsm[44] = logf(fsm[40] + fsm[41] + fsm[42] + fsm[43]);
        __syncthreads();
        float lse = fsm[44];
        if (tid < 21) {
            int row = b * 21 + tid;
            if (row < V_) p.out_logits[row] -= lse;
        }
    }
}

extern "C" void kernel_launch(void* const* d_in, const int* in_sizes, int n_in,
                              void* d_out, int out_size, void* d_ws, size_t ws_size,
                              hipStream_t stream) {
    Params prm;
    prm.enc          = (const float*)d_in[0];
    prm.word         = (const int*)  d_in[1];
    prm.last_context = (const float*)d_in[2];
    prm.h0           = (const float*)d_in[3];
    prm.c0           = (const float*)d_in[4];
    prm.emb          = (const float*)d_in[5];
    prm.W_ih         = (const float*)d_in[6];
    prm.W_hh         = (const float*)d_in[7];
    prm.b_ih         = (const float*)d_in[8];
    prm.b_hh         = (const float*)d_in[9];
    prm.W_attn       = (const float*)d_in[10];
    prm.b_attn       = (const float*)d_in[11];
    prm.v            = (const float*)d_in[12];
    prm.W_ah         = (const float*)d_in[13];
    prm.b_ah         = (const float*)d_in[14];
    prm.W_out        = (const float*)d_in[15];
    prm.b_out        = (const float*)d_in[16];

    float* out = (float*)d_out;
    prm.out_logits = out;                 // 32000
    prm.out_ht     = out + V_;            // 1024
    prm.out_c      = out + V_ + H_;       // 1024
    prm.out_htt    = out + V_ + 2 * H_;   // 1024
    prm.out_w      = out + V_ + 3 * H_;   // 2048

    float* ws = (float*)d_ws;
    prm.ws_ht  = ws;             // 1024
    prm.ws_q   = ws + 1024;      // 1024
    prm.ws_htt = ws + 2048;      // 1024
    prm.gpart  = ws + 3072;      // 256
    prm.ctx    = ws + 3328;      // 1024
    prm.lpart  = ws + 4352;      // 1536
    unsigned* syncarea = (unsigned*)(ws + 8192);
    prm.flagsB = syncarea;                      // 5 * 1536 = 7680
    prm.flags1 = syncarea + 5 * NB;             // 1024
    prm.go     = syncarea + 5 * NB + 1024;      // 8
    const int NSYNC = 5 * NB + 1024 + 8;        // 8712
    prm.spart  = ws + 20480;                    // 2048*32 = 65536
    prm.encb   = (unsigned short*)(ws + 90112); // 2048*1024 bf16
    prm.wab    = prm.encb + (size_t)S_ * E_;    // 1024*1024 bf16

    zeroK<<<(NSYNC + 63) / 64, 64, 0, stream>>>(syncarea, NSYNC, prm.ctx);
    mega<<<NB, 256, 0, stream>>>(prm);
}

// Round 8
// 84.866 us; speedup vs baseline: 5.6109x; 5.6109x over previous
//
#include <hip/hip_runtime.h>
#include <math.h>

#define V_ 32000
#define E_ 1024
#define H_ 1024
#define S_ 2048

typedef __attribute__((ext_vector_type(8))) short bf16x8;
typedef __attribute__((ext_vector_type(8))) unsigned short u16x8;
typedef __attribute__((ext_vector_type(4))) float f32x4;

typedef __attribute__((address_space(1))) const unsigned int gu32;
typedef __attribute__((address_space(3))) unsigned int lu32;

__device__ __forceinline__ float sigmoidf_(float x) { return 1.0f / (1.0f + expf(-x)); }

__device__ __forceinline__ unsigned short f2bf(float f) {
    unsigned int u = __builtin_bit_cast(unsigned int, f);
    unsigned int r = (u + 0x7fffu + ((u >> 16) & 1u)) >> 16;
    return (unsigned short)r;
}
__device__ __forceinline__ float bf2f(unsigned short u) {
    return __builtin_bit_cast(float, ((unsigned int)u) << 16);
}
__device__ __forceinline__ u16x8 pack8(float4 a, float4 b) {
    u16x8 p;
    p[0] = f2bf(a.x); p[1] = f2bf(a.y); p[2] = f2bf(a.z); p[3] = f2bf(a.w);
    p[4] = f2bf(b.x); p[5] = f2bf(b.y); p[6] = f2bf(b.z); p[7] = f2bf(b.w);
    return p;
}
__device__ __forceinline__ void gload16(const void* g, void* l) {
    __builtin_amdgcn_global_load_lds((gu32*)g, (lu32*)l, 16, 0, 0);
}

// ---------------- KA: LSTM (blocks 0..1023) || bf16 conversion (1024..1535) ----------------
__global__ __launch_bounds__(256) void kA(
    const float* __restrict__ W_ih, const float* __restrict__ W_hh,
    const float* __restrict__ b_ih, const float* __restrict__ b_hh,
    const float* __restrict__ last_context, const float* __restrict__ emb,
    const int* __restrict__ word, const float* __restrict__ h0,
    const float* __restrict__ c0, const float* __restrict__ enc,
    const float* __restrict__ W_attn,
    float* __restrict__ out_ht, float* __restrict__ out_c,
    float* __restrict__ ws_ht, unsigned short* __restrict__ encb,
    unsigned short* __restrict__ wab, float* __restrict__ ws_ctx)
{
    int b = blockIdx.x, tid = threadIdx.x;
    int wave = tid >> 6, lane = tid & 63;
    if (b < 1024) {
        __shared__ float sbuf[4];
        int j = b;
        const float* embrow = emb + (size_t)word[0] * E_;
        int row = j + wave * H_;
        const float* wi = W_ih + (size_t)row * (E_ + H_);
        const float* wh = W_hh + (size_t)row * H_;
        float acc = 0.f;
        #pragma unroll
        for (int it = 0; it < 8; ++it) {
            int idx = (lane + it * 64) * 4;
            float4 wv = *(const float4*)(wi + idx);
            float4 xv = (idx < H_) ? *(const float4*)(last_context + idx)
                                   : *(const float4*)(embrow + (idx - H_));
            acc = fmaf(wv.x, xv.x, acc); acc = fmaf(wv.y, xv.y, acc);
            acc = fmaf(wv.z, xv.z, acc); acc = fmaf(wv.w, xv.w, acc);
        }
        #pragma unroll
        for (int it = 0; it < 4; ++it) {
            int idx = (lane + it * 64) * 4;
            float4 wv = *(const float4*)(wh + idx);
            float4 hv = *(const float4*)(h0 + idx);
            acc = fmaf(wv.x, hv.x, acc); acc = fmaf(wv.y, hv.y, acc);
            acc = fmaf(wv.z, hv.z, acc); acc = fmaf(wv.w, hv.w, acc);
        }
        #pragma unroll
        for (int m = 32; m; m >>= 1) acc += __shfl_down(acc, m, 64);
        if (lane == 0) sbuf[wave] = acc;
        __syncthreads();
        if (tid == 0) {
            float gi = sbuf[0] + b_ih[j]          + b_hh[j];
            float gf = sbuf[1] + b_ih[j + H_]     + b_hh[j + H_];
            float gg = sbuf[2] + b_ih[j + 2*H_]   + b_hh[j + 2*H_];
            float go = sbuf[3] + b_ih[j + 3*H_]   + b_hh[j + 3*H_];
            float c  = sigmoidf_(gf) * c0[j] + sigmoidf_(gi) * tanhf(gg);
            float ht = sigmoidf_(go) * tanhf(c);
            out_c[j]  = c;
            out_ht[j] = ht;
            ws_ht[j]  = ht;
        }
        if (b == 0) {
            ws_ctx[tid]       = 0.f;
            ws_ctx[tid + 256] = 0.f;
            ws_ctx[tid + 512] = 0.f;
            ws_ctx[tid + 768] = 0.f;
        }
    } else {
        int cid = (b - 1024) * 256 + tid;
        const int ENC_CH = (S_ * E_) / 8;   // 262144
        #pragma unroll
        for (int i = 0; i < 3; ++i) {
            int idx = cid + i * 131072;
            const float* src;
            unsigned short* dst;
            if (idx < ENC_CH) {
                src = enc + (size_t)idx * 8;
                dst = encb + (size_t)idx * 8;
            } else {
                int w = idx - ENC_CH;
                int h = w >> 7, off = (w & 127) * 8;
                src = W_attn + (size_t)h * (E_ + H_) + H_ + off;
                dst = wab + (size_t)h * E_ + off;
            }
            float4 a = *(const float4*)src;
            float4 bq = *(const float4*)(src + 4);
            *(u16x8*)dst = pack8(a, bq);
        }
    }
}

// ---------------- KC: q-prologue + scores GEMM -> spart ----------------
// grid (32,16) = 512 blocks, 256 thr = 4 waves (2x2; wave tile 32x32).
// BM=64, BN=64, BK=64; single-buffered 16 KB LDS, 2-barrier loop.
// q computed per-block into LDS (redundant across the 32 blocks sharing by).
__global__ __launch_bounds__(256) void kC(
    const float* __restrict__ W_attn, const float* __restrict__ b_attn,
    const float* __restrict__ ws_ht,
    const unsigned short* __restrict__ encb, const unsigned short* __restrict__ wab,
    const float* __restrict__ v, float* __restrict__ spart)
{
    __shared__ unsigned short As[64 * 64];
    __shared__ unsigned short Bs[64 * 64];
    __shared__ float qsh[64], vsh[64];
    int bx = blockIdx.x, by = blockIdx.y;
    int s0 = bx * 64, h0 = by * 64;
    int tid = threadIdx.x;
    int wave = tid >> 6, lane = tid & 63;

    // ---- q prologue: wave w computes q rows h0 + w*16 .. +15 ----
    #pragma unroll 1
    for (int i = 0; i < 16; ++i) {
        int r = h0 + wave * 16 + i;
        const float* rowp = W_attn + (size_t)r * (E_ + H_);   // Wa_h part
        float acc = 0.f;
        #pragma unroll
        for (int it = 0; it < 4; ++it) {
            int idx = (lane + it * 64) * 4;
            float4 wv = *(const float4*)(rowp + idx);
            float4 hv = *(const float4*)(ws_ht + idx);
            acc = fmaf(wv.x, hv.x, acc); acc = fmaf(wv.y, hv.y, acc);
            acc = fmaf(wv.z, hv.z, acc); acc = fmaf(wv.w, hv.w, acc);
        }
        #pragma unroll
        for (int m = 32; m; m >>= 1) acc += __shfl_down(acc, m, 64);
        if (lane == 0) qsh[wave * 16 + i] = acc + b_attn[r];
    }
    if (tid < 64) vsh[tid] = v[h0 + tid];

    // ---- staging addresses (chunk-XOR swizzle; linear LDS dest) ----
    int r0 = tid >> 3, p0 = tid & 7;
    int lc = (p0 ^ (r0 & 7)) * 8;
    const unsigned short* aS0 = encb + (size_t)(s0 + r0) * E_ + lc;
    const unsigned short* aS1 = encb + (size_t)(s0 + 32 + r0) * E_ + lc;
    const unsigned short* bS0 = wab  + (size_t)(h0 + r0) * E_ + lc;
    const unsigned short* bS1 = wab  + (size_t)(h0 + 32 + r0) * E_ + lc;

    int wr = (wave >> 1) * 32, wc = (wave & 1) * 32;
    int fc = lane & 15, g = lane >> 4;
    int aRow[2], bRow[2], pc[2];
    #pragma unroll
    for (int m = 0; m < 2; ++m) aRow[m] = (wr + m * 16 + fc) * 64;
    #pragma unroll
    for (int n = 0; n < 2; ++n) bRow[n] = (wc + n * 16 + fc) * 64;
    #pragma unroll
    for (int kk = 0; kk < 2; ++kk) pc[kk] = ((kk * 4 + g) ^ (fc & 7)) * 8;

    f32x4 acc[2][2];
    #pragma unroll
    for (int m = 0; m < 2; ++m)
        #pragma unroll
        for (int n = 0; n < 2; ++n)
            acc[m][n] = (f32x4){0.f, 0.f, 0.f, 0.f};

    for (int t = 0; t < 16; ++t) {
        int k0 = t * 64;
        gload16(aS0 + k0, As + tid * 8);
        gload16(aS1 + k0, As + (tid + 256) * 8);
        gload16(bS0 + k0, Bs + tid * 8);
        gload16(bS1 + k0, Bs + (tid + 256) * 8);
        __syncthreads();
        #pragma unroll
        for (int kk = 0; kk < 2; ++kk) {
            bf16x8 af[2], bf2[2];
            #pragma unroll
            for (int m = 0; m < 2; ++m) af[m] = *(const bf16x8*)(As + aRow[m] + pc[kk]);
            #pragma unroll
            for (int n = 0; n < 2; ++n) bf2[n] = *(const bf16x8*)(Bs + bRow[n] + pc[kk]);
            #pragma unroll
            for (int m = 0; m < 2; ++m)
                #pragma unroll
                for (int n = 0; n < 2; ++n)
                    acc[m][n] = __builtin_amdgcn_mfma_f32_16x16x32_bf16(
                        af[m], bf2[n], acc[m][n], 0, 0, 0);
        }
        __syncthreads();
    }

    // ---- epilogue: partial scores ----
    float qv[2], vv[2];
    #pragma unroll
    for (int n = 0; n < 2; ++n) {
        int col = wc + n * 16 + fc;
        qv[n] = qsh[col];
        vv[n] = vsh[col];
    }
    int part = by * 2 + (wave & 1);
    #pragma unroll
    for (int m = 0; m < 2; ++m) {
        #pragma unroll
        for (int j = 0; j < 4; ++j) {
            float p = 0.f;
            #pragma unroll
            for (int n = 0; n < 2; ++n)
                p += tanhf(acc[m][n][j] + qv[n]) * vv[n];
            #pragma unroll
            for (int mask = 8; mask; mask >>= 1) p += __shfl_xor(p, mask, 64);
            if (fc == 0)
                spart[(size_t)(s0 + wr + m * 16 + g * 4 + j) * 32 + part] = p;
        }
    }
}

// ---------------- KD: e = exp(sum spart); gpart; ctxU += e * enc ----------------
// 128 blocks x 256 threads; block handles 16 s-rows.
__global__ __launch_bounds__(256) void kD(
    const float* __restrict__ spart, const unsigned short* __restrict__ encb,
    float* __restrict__ expw, float* __restrict__ gpart, float* __restrict__ ctx)
{
    __shared__ float esh[16];
    int b = blockIdx.x, tid = threadIdx.x;
    int s0 = b * 16;
    int sl = tid >> 4, pp = tid & 15;
    float vsum = spart[(size_t)(s0 + sl) * 32 + pp]
               + spart[(size_t)(s0 + sl) * 32 + pp + 16];
    #pragma unroll
    for (int mask = 8; mask; mask >>= 1) vsum += __shfl_xor(vsum, mask, 64);
    if (pp == 0) {
        float e = expf(vsum);
        expw[s0 + sl] = e;
        esh[sl] = e;
    }
    __syncthreads();
    if (tid == 0) {
        float bs = 0.f;
        #pragma unroll
        for (int i = 0; i < 16; ++i) bs += esh[i];
        gpart[b] = bs;
    }
    int e0 = tid * 4;
    float a0 = 0.f, a1 = 0.f, a2 = 0.f, a3 = 0.f;
    #pragma unroll
    for (int ss = 0; ss < 16; ++ss) {
        ushort4 u = *(const ushort4*)(encb + (size_t)(s0 + ss) * E_ + e0);
        float w = esh[ss];
        a0 = fmaf(w, bf2f(u.x), a0);
        a1 = fmaf(w, bf2f(u.y), a1);
        a2 = fmaf(w, bf2f(u.z), a2);
        a3 = fmaf(w, bf2f(u.w), a3);
    }
    atomicAdd(&ctx[e0 + 0], a0);
    atomicAdd(&ctx[e0 + 1], a1);
    atomicAdd(&ctx[e0 + 2], a2);
    atomicAdd(&ctx[e0 + 3], a3);
}

// ---------------- KE: ht_tilda = tanh(W_ah @ [ctxU/gS, ht] + b_ah); out_w ----------------
__global__ __launch_bounds__(64) void kE(
    const float* __restrict__ W_ah, const float* __restrict__ b_ah,
    const float* __restrict__ ctx, const float* __restrict__ ht,
    const float* __restrict__ gpart, const float* __restrict__ expw,
    float* __restrict__ out_htt, float* __restrict__ ws_htt,
    float* __restrict__ out_w)
{
    int b = blockIdx.x;
    int lane = threadIdx.x;
    float gsum = gpart[lane] + gpart[lane + 64];
    #pragma unroll
    for (int m = 32; m; m >>= 1) gsum += __shfl_xor(gsum, m, 64);
    float invS = 1.0f / gsum;
    if (b >= 1024) {
        int s = (b - 1024) * 256 + lane * 4;
        float4 e4 = *(const float4*)(expw + s);
        float4 w4 = { e4.x * invS, e4.y * invS, e4.z * invS, e4.w * invS };
        *(float4*)(out_w + s) = w4;
        return;
    }
    const float* row = W_ah + (size_t)b * (E_ + H_);
    float acc = 0.f;
    #pragma unroll
    for (int it = 0; it < 8; ++it) {
        int idx = (lane + it * 64) * 4;
        float4 wv = *(const float4*)(row + idx);
        float4 xv;
        if (idx < E_) {
            float4 cv = *(const float4*)(ctx + idx);
            xv = (float4){ cv.x * invS, cv.y * invS, cv.z * invS, cv.w * invS };
        } else {
            xv = *(const float4*)(ht + idx - E_);
        }
        acc = fmaf(wv.x, xv.x, acc); acc = fmaf(wv.y, xv.y, acc);
        acc = fmaf(wv.z, xv.z, acc); acc = fmaf(wv.w, xv.w, acc);
    }
    #pragma unroll
    for (int m = 32; m; m >>= 1) acc += __shfl_down(acc, m, 64);
    if (lane == 0) {
        float val = tanhf(acc + b_ah[b]);
        out_htt[b] = val;
        ws_htt[b]  = val;
    }
}

// ---------------- KF: logits (2 rows/wave) + per-block expsum ----------------
// 4000 blocks x 256 thr; 8 rows/block.
__global__ __launch_bounds__(256) void kF(
    const float* __restrict__ W_out, const float* __restrict__ b_out,
    const float* __restrict__ ht_tilda, float* __restrict__ logits,
    float* __restrict__ lpart)
{
    __shared__ float wes[4];
    int b = blockIdx.x;
    int wave = threadIdx.x >> 6, lane = threadIdx.x & 63;
    int r0 = b * 8 + wave * 2;
    const float* w0 = W_out + (size_t)r0 * H_;
    const float* w1 = W_out + (size_t)(r0 + 1) * H_;
    float a0 = 0.f, a1 = 0.f;
    #pragma unroll
    for (int it = 0; it < 4; ++it) {
        int idx = (lane + it * 64) * 4;
        float4 hv = *(const float4*)(ht_tilda + idx);
        float4 v0 = *(const float4*)(w0 + idx);
        float4 v1 = *(const float4*)(w1 + idx);
        a0 = fmaf(v0.x, hv.x, a0); a0 = fmaf(v0.y, hv.y, a0);
        a0 = fmaf(v0.z, hv.z, a0); a0 = fmaf(v0.w, hv.w, a0);
        a1 = fmaf(v1.x, hv.x, a1); a1 = fmaf(v1.y, hv.y, a1);
        a1 = fmaf(v1.z, hv.z, a1); a1 = fmaf(v1.w, hv.w, a1);
    }
    #pragma unroll
    for (int m = 32; m; m >>= 1) {
        a0 += __shfl_down(a0, m, 64);
        a1 += __shfl_down(a1, m, 64);
    }
    if (lane == 0) {
        float lg0 = a0 + b_out[r0];
        float lg1 = a1 + b_out[r0 + 1];
        logits[r0]     = lg0;
        logits[r0 + 1] = lg1;
        wes[wave] = expf(lg0) + expf(lg1);
    }
    __syncthreads();
    if (threadIdx.x == 0)
        lpart[b] = wes[0] + wes[1] + wes[2] + wes[3];
}

// ---------------- KG: lse (redundant x8) + subtract ----------------
// 8 blocks x 1024 thr; each block handles 4000 logit rows.
__global__ __launch_bounds__(1024) void kG(
    float* __restrict__ out, const float* __restrict__ lpart)
{
    __shared__ float sred[16];
    int b = blockIdx.x, tid = threadIdx.x;
    float s = 0.f;
    #pragma unroll
    for (int k = 0; k < 4; ++k) {
        int i = tid + k * 1024;
        if (i < 4000) s += lpart[i];
    }
    #pragma unroll
    for (int m = 32; m; m >>= 1) s += __shfl_down(s, m, 64);
    if ((tid & 63) == 0) sred[tid >> 6] = s;
    __syncthreads();
    float tot = 0.f;
    #pragma unroll
    for (int i = 0; i < 16; ++i) tot += sred[i];
    float lse = logf(tot);
    #pragma unroll
    for (int k = 0; k < 4; ++k) {
        int row = b * 4000 + k * 1024 + tid;
        if (row < (b + 1) * 4000 && row < V_) out[row] -= lse;
    }
}

extern "C" void kernel_launch(void* const* d_in, const int* in_sizes, int n_in,
                              void* d_out, int out_size, void* d_ws, size_t ws_size,
                              hipStream_t stream) {
    const float* enc          = (const float*)d_in[0];
    const int*   word         = (const int*)  d_in[1];
    const float* last_context = (const float*)d_in[2];
    const float* h0           = (const float*)d_in[3];
    const float* c0           = (const float*)d_in[4];
    const float* emb          = (const float*)d_in[5];
    const float* W_ih         = (const float*)d_in[6];
    const float* W_hh         = (const float*)d_in[7];
    const float* b_ih         = (const float*)d_in[8];
    const float* b_hh         = (const float*)d_in[9];
    const float* W_attn       = (const float*)d_in[10];
    const float* b_attn       = (const float*)d_in[11];
    const float* v            = (const float*)d_in[12];
    const float* W_ah         = (const float*)d_in[13];
    const float* b_ah         = (const float*)d_in[14];
    const float* W_out        = (const float*)d_in[15];
    const float* b_out        = (const float*)d_in[16];

    float* out        = (float*)d_out;
    float* out_logits = out;                 // 32000
    float* out_ht     = out + V_;            // 1024
    float* out_c      = out + V_ + H_;       // 1024
    float* out_htt    = out + V_ + 2 * H_;   // 1024
    float* out_w      = out + V_ + 3 * H_;   // 2048

    float* ws      = (float*)d_ws;
    float* ws_ht   = ws;             // 1024
    float* ws_expw = ws + 1024;      // 2048
    float* ws_ctx  = ws + 3072;      // 1024
    float* ws_gp   = ws + 4096;      // 128
    float* ws_htt  = ws + 4224;      // 1024
    float* ws_lp   = ws + 5248;      // 4000
    float* ws_sp   = ws + 16384;     // 2048*32
    unsigned short* encb = (unsigned short*)(ws + 81920);  // 2048*1024 bf16
    unsigned short* wab  = encb + (size_t)S_ * E_;         // 1024*1024 bf16

    kA<<<1536, 256, 0, stream>>>(W_ih, W_hh, b_ih, b_hh, last_context, emb, word,
                                 h0, c0, enc, W_attn, out_ht, out_c, ws_ht,
                                 encb, wab, ws_ctx);
    kC<<<dim3(32, 16), 256, 0, stream>>>(W_attn, b_attn, ws_ht, encb, wab, v, ws_sp);
    kD<<<128, 256, 0, stream>>>(ws_sp, encb, ws_expw, ws_gp, ws_ctx);
    kE<<<1032, 64, 0, stream>>>(W_ah, b_ah, ws_ctx, ws_ht, ws_gp, ws_expw,
                                out_htt, ws_htt, out_w);
    kF<<<4000, 256, 0, stream>>>(W_out, b_out, ws_htt, out_logits, ws_lp);
    kG<<<8, 1024, 0, stream>>>(out_logits, ws_lp);
}